// Round 6
// baseline (12.395 us; speedup 1.0000x reference)
//
#include <hip/hip_runtime.h>

#define BN_EPS 1e-3f

// Kernel 1: per-node partial sums, wave-per-row (lane = feature), 4 rows/block.
// Si[b*N+n] = sum_f relu(feat[b,n,f]*inv[1+f]   + bias[1+f])   * w[1+f]
// Sj[b*N+n] = sum_f relu(feat[b,n,f]*inv[1+F+f] + bias[1+F+f]) * w[1+F+f]
__global__ __launch_bounds__(256) void node_sums_kernel(
    const float* __restrict__ feat,   // [B,N,F]
    const float* __restrict__ gamma,
    const float* __restrict__ beta,
    const float* __restrict__ mean,
    const float* __restrict__ var,
    const float* __restrict__ w,
    float* __restrict__ Si,
    float* __restrict__ Sj,
    int F, int BN) {
    const int lane = threadIdx.x & 63;
    const int row  = (blockIdx.x * blockDim.x + threadIdx.x) >> 6;  // b*N + n
    if (row >= BN) return;

    const bool act = (lane < F);
    const int  fl  = act ? lane : (F - 1);
    const int  ci  = 1 + fl;
    const int  cj  = 1 + F + fl;

    const float invi = gamma[ci] * rsqrtf(var[ci] + BN_EPS);
    const float bi   = beta[ci] - mean[ci] * invi;
    const float invj = gamma[cj] * rsqrtf(var[cj] + BN_EPS);
    const float bj   = beta[cj] - mean[cj] * invj;

    const float x = feat[(long long)row * F + fl];
    float vi = act ? fmaxf(fmaf(x, invi, bi), 0.0f) * w[ci] : 0.0f;
    float vj = act ? fmaxf(fmaf(x, invj, bj), 0.0f) * w[cj] : 0.0f;

    #pragma unroll
    for (int off = 32; off > 0; off >>= 1) {
        vi += __shfl_down(vi, off, 64);
        vj += __shfl_down(vj, off, 64);
    }
    if (lane == 0) {
        Si[row] = vi;
        Sj[row] = vj;
    }
}

// Kernel 2 (pow2-N fast path): 8 elements (2 contiguous float4) per thread.
// out[b,i,j] = relu(adj*inv0 + b0)*w0 + Si[b*N+i] + Sj[b*N+j] + cb
// UNI: a wave's 8*64=512 elements lie within one row -> row is wave-uniform.
template<bool UNI>
__global__ __launch_bounds__(256) void out_kernel_pow2(
    const float* __restrict__ adj,
    const float* __restrict__ Si,
    const float* __restrict__ Sj,
    float* __restrict__ out,
    const float* __restrict__ gamma,
    const float* __restrict__ beta,
    const float* __restrict__ mean,
    const float* __restrict__ var,
    const float* __restrict__ w,
    const float* __restrict__ conv_b,
    int logN, int total8) {
    const int t = blockIdx.x * blockDim.x + threadIdx.x;
    if (t >= total8) return;

    const float inv0 = gamma[0] * rsqrtf(var[0] + BN_EPS);
    const float b0   = beta[0] - mean[0] * inv0;
    const float w0   = w[0];
    const float cb   = conv_b[0];

    const int idx = t << 3;                        // flat element index
    int row = idx >> logN;                         // b*N + i
    if (UNI) row = __builtin_amdgcn_readfirstlane(row);
    const int j0 = idx & ((1 << logN) - 1);
    const int bN = (row >> logN) << logN;          // b*N

    const float4* a4  = reinterpret_cast<const float4*>(adj);
    const float4* sj4 = reinterpret_cast<const float4*>(Sj + bN + j0);
    float4*       o4  = reinterpret_cast<float4*>(out);

    // issue all loads first (ILP)
    const float4 a0 = a4[2 * t];
    const float4 a1 = a4[2 * t + 1];
    const float4 s0 = sj4[0];
    const float4 s1 = sj4[1];
    const float  si = Si[row] + cb;

    float4 r0, r1;
    r0.x = fmaxf(fmaf(a0.x, inv0, b0), 0.0f) * w0 + si + s0.x;
    r0.y = fmaxf(fmaf(a0.y, inv0, b0), 0.0f) * w0 + si + s0.y;
    r0.z = fmaxf(fmaf(a0.z, inv0, b0), 0.0f) * w0 + si + s0.z;
    r0.w = fmaxf(fmaf(a0.w, inv0, b0), 0.0f) * w0 + si + s0.w;
    r1.x = fmaxf(fmaf(a1.x, inv0, b0), 0.0f) * w0 + si + s1.x;
    r1.y = fmaxf(fmaf(a1.y, inv0, b0), 0.0f) * w0 + si + s1.y;
    r1.z = fmaxf(fmaf(a1.z, inv0, b0), 0.0f) * w0 + si + s1.z;
    r1.w = fmaxf(fmaf(a1.w, inv0, b0), 0.0f) * w0 + si + s1.w;

    o4[2 * t]     = r0;
    o4[2 * t + 1] = r1;
}

// Kernel 2 (generic fallback, R5 structure): one float4 per thread, divides.
__global__ __launch_bounds__(256) void out_kernel_gen(
    const float* __restrict__ adj,
    const float* __restrict__ Si,
    const float* __restrict__ Sj,
    float* __restrict__ out,
    const float* __restrict__ gamma,
    const float* __restrict__ beta,
    const float* __restrict__ mean,
    const float* __restrict__ var,
    const float* __restrict__ w,
    const float* __restrict__ conv_b,
    int N, int total4) {
    const int t = blockIdx.x * blockDim.x + threadIdx.x;
    if (t >= total4) return;

    const float inv0 = gamma[0] * rsqrtf(var[0] + BN_EPS);
    const float b0   = beta[0] - mean[0] * inv0;
    const float w0   = w[0];
    const float cb   = conv_b[0];

    const float4 a = reinterpret_cast<const float4*>(adj)[t];

    const int idx = t * 4;
    const int row = idx / N;
    const int b   = row / N;
    const int j0  = idx - row * N;

    const float  si = Si[row] + cb;
    const float4 s  = *reinterpret_cast<const float4*>(Sj + b * N + j0);

    float4 r;
    r.x = fmaxf(fmaf(a.x, inv0, b0), 0.0f) * w0 + si + s.x;
    r.y = fmaxf(fmaf(a.y, inv0, b0), 0.0f) * w0 + si + s.y;
    r.z = fmaxf(fmaf(a.z, inv0, b0), 0.0f) * w0 + si + s.z;
    r.w = fmaxf(fmaf(a.w, inv0, b0), 0.0f) * w0 + si + s.w;

    reinterpret_cast<float4*>(out)[t] = r;
}

extern "C" void kernel_launch(void* const* d_in, const int* in_sizes, int n_in,
                              void* d_out, int out_size, void* d_ws, size_t ws_size,
                              hipStream_t stream) {
    const float* feat  = (const float*)d_in[0];   // [B,N,F]
    const float* adj   = (const float*)d_in[1];   // [B,N,N]
    const float* gamma = (const float*)d_in[2];   // [C]
    const float* beta  = (const float*)d_in[3];
    const float* mean  = (const float*)d_in[4];
    const float* var   = (const float*)d_in[5];
    const float* w     = (const float*)d_in[6];
    const float* cb    = (const float*)d_in[7];   // [1]

    const int C  = in_sizes[2];
    const int F  = (C - 1) / 2;                   // 64
    const int BN = in_sizes[0] / F;               // B*N = 2048
    const long long total = in_sizes[1];          // B*N*N
    const int N  = (int)(total / BN);             // 512

    float* Si = (float*)d_ws;                     // BN floats
    float* Sj = Si + BN;                          // BN floats

    const int blocks1 = (BN * 64 + 255) / 256;    // 512
    node_sums_kernel<<<blocks1, 256, 0, stream>>>(feat, gamma, beta, mean, var,
                                                  w, Si, Sj, F, BN);

    const bool pow2 = (N & (N - 1)) == 0 && (N % 8) == 0;
    if (pow2) {
        int logN = 0;
        while ((1 << logN) < N) ++logN;
        const int total8  = (int)(total / 8);
        const int blocks2 = (total8 + 255) / 256;
        if (N >= 512) {
            out_kernel_pow2<true><<<blocks2, 256, 0, stream>>>(
                adj, Si, Sj, (float*)d_out, gamma, beta, mean, var, w, cb,
                logN, total8);
        } else {
            out_kernel_pow2<false><<<blocks2, 256, 0, stream>>>(
                adj, Si, Sj, (float*)d_out, gamma, beta, mean, var, w, cb,
                logN, total8);
        }
    } else {
        const int total4  = (int)(total / 4);
        const int blocks2 = (total4 + 255) / 256;
        out_kernel_gen<<<blocks2, 256, 0, stream>>>(
            adj, Si, Sj, (float*)d_out, gamma, beta, mean, var, w, cb,
            N, total4);
    }
}

// Round 7
// 12.220 us; speedup vs baseline: 1.0143x; 1.0143x over previous
//
#include <hip/hip_runtime.h>

#define BN_EPS 1e-3f

// Kernel 1: per-node partial sums, wave-per-row (lane = feature), 4 rows/block.
// Si[b*N+n] = sum_f relu(feat[b,n,f]*inv[1+f]   + bias[1+f])   * w[1+f]
// Sj[b*N+n] = sum_f relu(feat[b,n,f]*inv[1+F+f] + bias[1+F+f]) * w[1+F+f]
__global__ __launch_bounds__(256) void node_sums_kernel(
    const float* __restrict__ feat,   // [B,N,F]
    const float* __restrict__ gamma,
    const float* __restrict__ beta,
    const float* __restrict__ mean,
    const float* __restrict__ var,
    const float* __restrict__ w,
    float* __restrict__ Si,
    float* __restrict__ Sj,
    int F, int BN) {
    const int lane = threadIdx.x & 63;
    const int row  = (blockIdx.x * blockDim.x + threadIdx.x) >> 6;  // b*N + n
    if (row >= BN) return;

    const bool act = (lane < F);
    const int  fl  = act ? lane : (F - 1);
    const int  ci  = 1 + fl;
    const int  cj  = 1 + F + fl;

    const float invi = gamma[ci] * rsqrtf(var[ci] + BN_EPS);
    const float bi   = beta[ci] - mean[ci] * invi;
    const float invj = gamma[cj] * rsqrtf(var[cj] + BN_EPS);
    const float bj   = beta[cj] - mean[cj] * invj;

    const float x = feat[(long long)row * F + fl];
    float vi = act ? fmaxf(fmaf(x, invi, bi), 0.0f) * w[ci] : 0.0f;
    float vj = act ? fmaxf(fmaf(x, invj, bj), 0.0f) * w[cj] : 0.0f;

    #pragma unroll
    for (int off = 32; off > 0; off >>= 1) {
        vi += __shfl_down(vi, off, 64);
        vj += __shfl_down(vj, off, 64);
    }
    if (lane == 0) {
        Si[row] = vi;
        Sj[row] = vj;
    }
}

// Kernel 2: out[b,i,j] = relu(adj*inv0 + bias0)*w0 + Si[b*N+i] + Sj[b*N+j] + cb
// One float4 per thread over flat [B*N*N]; N % 4 == 0. With 256-thread blocks,
// each wave covers exactly half an output row -> `row` is wave-uniform.
__global__ __launch_bounds__(256) void out_kernel(
    const float* __restrict__ adj,
    const float* __restrict__ Si,
    const float* __restrict__ Sj,
    float* __restrict__ out,
    const float* __restrict__ gamma,
    const float* __restrict__ beta,
    const float* __restrict__ mean,
    const float* __restrict__ var,
    const float* __restrict__ w,
    const float* __restrict__ conv_b,
    int N, int total4) {
    const int t = blockIdx.x * blockDim.x + threadIdx.x;
    if (t >= total4) return;

    const float inv0 = gamma[0] * rsqrtf(var[0] + BN_EPS);
    const float b0   = beta[0] - mean[0] * inv0;
    const float w0   = w[0];
    const float cb   = conv_b[0];

    const float4 a = reinterpret_cast<const float4*>(adj)[t];

    const int idx = t * 4;                       // flat index into [B*N*N]
    const int row = __builtin_amdgcn_readfirstlane(idx / N);  // wave-uniform: b*N+i
    const int b   = row / N;                     // batch
    const int j0  = idx - row * N;

    const float  si = Si[row] + cb;              // scalar (SGPR) load
    const float4 s  = *reinterpret_cast<const float4*>(Sj + b * N + j0);

    float4 r;
    r.x = fmaxf(fmaf(a.x, inv0, b0), 0.0f) * w0 + si + s.x;
    r.y = fmaxf(fmaf(a.y, inv0, b0), 0.0f) * w0 + si + s.y;
    r.z = fmaxf(fmaf(a.z, inv0, b0), 0.0f) * w0 + si + s.z;
    r.w = fmaxf(fmaf(a.w, inv0, b0), 0.0f) * w0 + si + s.w;

    reinterpret_cast<float4*>(out)[t] = r;
}

extern "C" void kernel_launch(void* const* d_in, const int* in_sizes, int n_in,
                              void* d_out, int out_size, void* d_ws, size_t ws_size,
                              hipStream_t stream) {
    const float* feat  = (const float*)d_in[0];   // [B,N,F]
    const float* adj   = (const float*)d_in[1];   // [B,N,N]
    const float* gamma = (const float*)d_in[2];   // [C]
    const float* beta  = (const float*)d_in[3];
    const float* mean  = (const float*)d_in[4];
    const float* var   = (const float*)d_in[5];
    const float* w     = (const float*)d_in[6];
    const float* cb    = (const float*)d_in[7];   // [1]

    const int C  = in_sizes[2];
    const int F  = (C - 1) / 2;                   // 64
    const int BN = in_sizes[0] / F;               // B*N = 2048
    const long long total = in_sizes[1];          // B*N*N
    const int N  = (int)(total / BN);             // 512

    float* Si = (float*)d_ws;                     // BN floats
    float* Sj = Si + BN;                          // BN floats

    // kernel 1: 4 wave-rows per 256-thread block
    const int blocks1 = (BN * 64 + 255) / 256;    // 512
    node_sums_kernel<<<blocks1, 256, 0, stream>>>(feat, gamma, beta, mean, var,
                                                  w, Si, Sj, F, BN);

    const int total4  = (int)(total / 4);
    const int blocks2 = (total4 + 255) / 256;     // 2048
    out_kernel<<<blocks2, 256, 0, stream>>>(adj, Si, Sj, (float*)d_out,
                                            gamma, beta, mean, var, w, cb,
                                            N, total4);
}